// Round 19
// baseline (47.935 us; speedup 1.0000x reference)
//
#include <hip/hip_runtime.h>
#include <hip/hip_bf16.h>

#define LL 128
#define HH 768
#define OFF_REL  0
#define OFF_MASK 131072
#define OFF_HSRC 131840
#define OFF_HTGT 918272
#define SCALEC 2.8853900817779268f   // 2*log2(e):  e^{2x} = exp2(SCALEC*x)

typedef __attribute__((ext_vector_type(8))) short short8;
typedef __attribute__((ext_vector_type(4))) float floatx4;

__device__ inline unsigned short f2bf(float f) {
  unsigned u = __float_as_uint(f);
  u += 0x7FFFu + ((u >> 16) & 1u);
  return (unsigned short)(u >> 16);
}
__device__ __forceinline__ float bf2f(unsigned short u) {
  return __uint_as_float(((unsigned)u) << 16);
}
struct us4 { unsigned short x, y, z, w; };

__device__ __forceinline__ void gload16(const void* g, void* l) {
  __builtin_amdgcn_global_load_lds(
      (const __attribute__((address_space(1))) unsigned int*)g,
      (__attribute__((address_space(3))) unsigned int*)l,
      16, 0, 0);
}

// ---------------- fp32 -> bf16: hidden + all three weights ----------------
__global__ __launch_bounds__(256) void cvt_kernel(
    const float4* __restrict__ hs, const float4* __restrict__ wsrc,
    const float4* __restrict__ wtgt, const float4* __restrict__ wd,
    us4* __restrict__ ab, us4* __restrict__ wb)
{
  const int n0 = 49152;
  const int n1 = n0 + 589824;
  const int n2 = n1 + 589824;
  const int n3 = n2 + 442368;
  int stride = gridDim.x * blockDim.x;
  for (int i = blockIdx.x * blockDim.x + threadIdx.x; i < n3; i += stride) {
    const float4* src; us4* dst;
    if (i < n0)      { src = hs   + i;        dst = ab + i; }
    else if (i < n1) { src = wsrc + (i - n0); dst = wb + (i - n0); }
    else if (i < n2) { src = wtgt + (i - n1); dst = wb + 589824 + (i - n1); }
    else             { src = wd   + (i - n2); dst = wb + 1179648 + (i - n2); }
    float4 v = *src;
    us4 o; o.x = f2bf(v.x); o.y = f2bf(v.y); o.z = f2bf(v.z); o.w = f2bf(v.w);
    *dst = o;
  }
}

// ---------------- GEMM (R18, validated): depth-3 counted-vmcnt, BK=64, swizzled LDS ----------------
__global__ __launch_bounds__(256, 2) void gemm_kernel(
    const unsigned short* __restrict__ Ab, const unsigned short* __restrict__ Wb,
    const float* __restrict__ b_src, const float* __restrict__ b_tgt,
    const float* __restrict__ dense_b,
    float* __restrict__ out, float* __restrict__ z,
    unsigned short* __restrict__ Esb, unsigned short* __restrict__ Etb)
{
  __shared__ __align__(1024) char sAB[4][16384];
  int tid = threadIdx.x;
  int wave = tid >> 6, lane = tid & 63;
  int nb = blockIdx.x, rb = blockIdx.y;
  int gcol0 = nb * 64, grow0 = rb * 64;
  int which = (nb < 48) ? 0 : (nb < 96) ? 1 : 2;

  int r0 = tid >> 3, c0 = tid & 7;
  int c0s = c0 ^ (r0 & 7);
  const unsigned short* gA0 = Ab + (long)(grow0 + r0) * HH + c0s * 8;
  const unsigned short* gA1 = gA0 + 32 * HH;
  const unsigned short* gB0 = Wb + (long)(gcol0 + r0) * HH + c0s * 8;
  const unsigned short* gB1 = gB0 + 32 * HH;

  int lr = lane & 15, hi = lane >> 4;
  int wm = (wave >> 1) * 32, wn = (wave & 1) * 32;
  int swz = lr & 7;

  floatx4 acc[2][2];
  #pragma unroll
  for (int mi = 0; mi < 2; ++mi)
    #pragma unroll
    for (int ni = 0; ni < 2; ++ni)
      acc[mi][ni] = (floatx4){0.f, 0.f, 0.f, 0.f};

#define STAGE(BUF, KT) do {                                       \
    char* b_ = &sAB[BUF][0];                                      \
    gload16(gA0 + (KT) * 64, b_ + wave * 1024);                   \
    gload16(gA1 + (KT) * 64, b_ + 4096 + wave * 1024);            \
    gload16(gB0 + (KT) * 64, b_ + 8192 + wave * 1024);            \
    gload16(gB1 + (KT) * 64, b_ + 12288 + wave * 1024);           \
  } while (0)

  STAGE(0, 0);
  STAGE(1, 1);
  STAGE(2, 2);

  #pragma unroll
  for (int kt = 0; kt < 12; ++kt) {
    int buf = kt & 3;
    if (kt <= 8) {
      STAGE((kt + 3) & 3, kt + 3);
      asm volatile("s_waitcnt vmcnt(12)" ::: "memory");
    } else if (kt == 9) {
      asm volatile("s_waitcnt vmcnt(8)" ::: "memory");
    } else if (kt == 10) {
      asm volatile("s_waitcnt vmcnt(4)" ::: "memory");
    } else {
      asm volatile("s_waitcnt vmcnt(0)" ::: "memory");
    }
    __builtin_amdgcn_sched_barrier(0);
    __builtin_amdgcn_s_barrier();
    __builtin_amdgcn_sched_barrier(0);

    const char* bA = &sAB[buf][0];
    const char* bB = bA + 8192;
    #pragma unroll
    for (int ks = 0; ks < 2; ++ks) {
      int cs = ((ks * 4 + hi) ^ swz) * 16;
      short8 a0 = *(const short8*)(bA + (wm + lr) * 128 + cs);
      short8 a1 = *(const short8*)(bA + (wm + 16 + lr) * 128 + cs);
      short8 b0 = *(const short8*)(bB + (wn + lr) * 128 + cs);
      short8 b1 = *(const short8*)(bB + (wn + 16 + lr) * 128 + cs);
      acc[0][0] = __builtin_amdgcn_mfma_f32_16x16x32_bf16(a0, b0, acc[0][0], 0, 0, 0);
      acc[0][1] = __builtin_amdgcn_mfma_f32_16x16x32_bf16(a0, b1, acc[0][1], 0, 0, 0);
      acc[1][0] = __builtin_amdgcn_mfma_f32_16x16x32_bf16(a1, b0, acc[1][0], 0, 0, 0);
      acc[1][1] = __builtin_amdgcn_mfma_f32_16x16x32_bf16(a1, b1, acc[1][1], 0, 0, 0);
    }

    __builtin_amdgcn_sched_barrier(0);
    __builtin_amdgcn_s_barrier();
  }
#undef STAGE

  int lrow = hi * 4;
  #pragma unroll
  for (int mi = 0; mi < 2; ++mi)
  #pragma unroll
  for (int ni = 0; ni < 2; ++ni) {
    int colg = gcol0 + wn + ni * 16 + lr;
    int row0 = grow0 + wm + mi * 16 + lrow;
    if (which == 0) {
      float bv = b_src[colg];
      #pragma unroll
      for (int r2 = 0; r2 < 4; ++r2) {
        int row = row0 + r2;
        float v = acc[mi][ni][r2] + bv;
        out[OFF_HSRC + row * 3072 + colg] = v;
        Esb[row * 3072 + colg] = f2bf(__builtin_amdgcn_exp2f(SCALEC * v));
      }
    } else if (which == 1) {
      int cc = colg - 3072;
      float bv = b_tgt[cc];
      #pragma unroll
      for (int r2 = 0; r2 < 4; ++r2) {
        int row = row0 + r2;
        float v = acc[mi][ni][r2] + bv;
        out[OFF_HTGT + row * 3072 + cc] = v;
        Etb[row * 3072 + cc] = f2bf(__builtin_amdgcn_exp2f(SCALEC * v));
      }
    } else {
      int cc = colg - 6144;
      float bv = dense_b[cc];
      #pragma unroll
      for (int r2 = 0; r2 < 4; ++r2)
        z[(row0 + r2) * 2304 + cc] = acc[mi][ni][r2] + bv;
    }
  }
}

// ---------------- pairwise relation + token-mask head ----------------
// bf16 Es/Et tiles staged ONCE (whole 768-h range), single barrier, trans-bound loop.
#define PADW 776
__global__ __launch_bounds__(512) void pair_kernel(
    const unsigned short* __restrict__ Esb, const unsigned short* __restrict__ Etb,
    const float* __restrict__ w_out,
    const float* __restrict__ z, const float* __restrict__ clf_W,
    const float* __restrict__ clf_b, float* __restrict__ out)
{
  int tid = threadIdx.x;

  if (blockIdx.z == 8) {
    // token mask head (z fp32, unchanged)
    int blk = blockIdx.y * 8 + blockIdx.x;
    int wave = tid >> 6, lane = tid & 63;
    int slot = blk * 8 + wave;
    for (int o = slot; o < 768; o += 512) {
      int b = o / 384, rem = o - b * 384;
      int t = rem >> 7, lt = rem & 127;
      const float* zr = z + (long)(b * LL + lt) * 2304 + t * HH;
      float acc = 0.f;
      for (int h = lane; h < HH; h += 64) {
        float x = zr[h];
        float th = 1.f - 2.f * __builtin_amdgcn_rcpf(1.f + __builtin_amdgcn_exp2f(SCALEC * x));
        acc = fmaf(clf_W[h], th, acc);
      }
      #pragma unroll
      for (int d = 32; d; d >>= 1) acc += __shfl_down(acc, d);
      if (lane == 0) out[OFF_MASK + o] = acc + clf_b[0];
    }
    return;
  }

  __shared__ unsigned short sA[16][PADW];   // 24832 B
  __shared__ unsigned short sB[16][PADW];   // 24832 B
  __shared__ __align__(16) float sW[768];   // 3072 B
  __shared__ float sRed[2048];              // 8192 B
  __shared__ float sWsum;

  int g = tid >> 6, lane = tid & 63;
  int sq = lane >> 3, tq = lane & 7;
  int t0 = blockIdx.x * 16, s0 = blockIdx.y * 16;
  int br = blockIdx.z, bb = br >> 2, r = br & 3;

  if (tid < 64) {
    float wsm = 0.f;
    for (int h = tid; h < HH; h += 64) wsm += w_out[h];
    #pragma unroll
    for (int d = 32; d; d >>= 1) wsm += __shfl_down(wsm, d);
    if (tid == 0) sWsum = wsm;
  }
  if (tid >= 64 && tid < 256) *(float4*)&sW[(tid - 64) * 4] = *(const float4*)(w_out + (tid - 64) * 4);

  // one-shot staging: 1536 uint4 per matrix (16 rows x 96 slots of 8 bf16)
  #pragma unroll
  for (int j = 0; j < 3; ++j) {
    int idx = j * 512 + tid;
    int row = idx / 96, c8 = idx - row * 96;
    *(uint4*)&sA[row][c8 * 8] =
        *(const uint4*)(Esb + (long)(bb * LL + s0 + row) * 3072 + r * HH + c8 * 8);
    *(uint4*)&sB[row][c8 * 8] =
        *(const uint4*)(Etb + (long)(bb * LL + t0 + row) * 3072 + r * HH + c8 * 8);
  }
  __syncthreads();

  float a00 = 0.f, a01 = 0.f, a10 = 0.f, a11 = 0.f;
  const unsigned short* pA0 = &sA[2 * sq][g * 96];
  const unsigned short* pA1 = &sA[2 * sq + 1][g * 96];
  const unsigned short* pB0 = &sB[2 * tq][g * 96];
  const unsigned short* pB1 = &sB[2 * tq + 1][g * 96];
  const float* pW = &sW[g * 96];

  #pragma unroll
  for (int st = 0; st < 12; ++st) {
    short8 ua0 = *(const short8*)(pA0 + st * 8);
    short8 ua1 = *(const short8*)(pA1 + st * 8);
    short8 ub0 = *(const short8*)(pB0 + st * 8);
    short8 ub1 = *(const short8*)(pB1 + st * 8);
    float4 wv0 = *(const float4*)(pW + st * 8);
    float4 wv1 = *(const float4*)(pW + st * 8 + 4);
    #pragma unroll
    for (int q = 0; q < 8; ++q) {
      float e0 = bf2f((unsigned short)ua0[q]);
      float e1 = bf2f((unsigned short)ua1[q]);
      float f0 = bf2f((unsigned short)ub0[q]);
      float f1 = bf2f((unsigned short)ub1[q]);
      float w = (q < 4) ? ((q == 0) ? wv0.x : (q == 1) ? wv0.y : (q == 2) ? wv0.z : wv0.w)
                        : ((q == 4) ? wv1.x : (q == 5) ? wv1.y : (q == 6) ? wv1.z : wv1.w);
      a00 = fmaf(w, __builtin_amdgcn_rcpf(fmaf(e0, f0, 1.f)), a00);
      a01 = fmaf(w, __builtin_amdgcn_rcpf(fmaf(e0, f1, 1.f)), a01);
      a10 = fmaf(w, __builtin_amdgcn_rcpf(fmaf(e1, f0, 1.f)), a10);
      a11 = fmaf(w, __builtin_amdgcn_rcpf(fmaf(e1, f1, 1.f)), a11);
    }
  }

  sRed[0 * 512 + g * 64 + lane] = a00;
  sRed[1 * 512 + g * 64 + lane] = a01;
  sRed[2 * 512 + g * 64 + lane] = a10;
  sRed[3 * 512 + g * 64 + lane] = a11;
  __syncthreads();
  if (tid < 256) {
    int s = tid >> 4, t = tid & 15;
    int pp = (s >> 1) * 8 + (t >> 1);
    int sl = (s & 1) * 2 + (t & 1);
    float sum = 0.f;
    #pragma unroll
    for (int gg = 0; gg < 8; ++gg) sum += sRed[sl * 512 + gg * 64 + pp];
    out[((long)br * LL + (s0 + s)) * LL + (t0 + t)] = sWsum - 2.f * sum;
  }
}

extern "C" void kernel_launch(void* const* d_in, const int* in_sizes, int n_in,
                              void* d_out, int out_size, void* d_ws, size_t ws_size,
                              hipStream_t stream)
{
  const float* hidden  = (const float*)d_in[0];
  const float* W_src   = (const float*)d_in[1];
  const float* b_src   = (const float*)d_in[2];
  const float* W_tgt   = (const float*)d_in[3];
  const float* b_tgt   = (const float*)d_in[4];
  const float* w_out   = (const float*)d_in[5];
  const float* dense_W = (const float*)d_in[6];
  const float* dense_b = (const float*)d_in[7];
  const float* clf_W   = (const float*)d_in[8];
  const float* clf_b   = (const float*)d_in[9];
  float* out = (float*)d_out;
  char* ws = (char*)d_ws;

  unsigned short* Ab  = (unsigned short*)ws;            // 256x768 bf16
  unsigned short* Wb  = (unsigned short*)(ws + 393216); // 8448x768 bf16
  float* z            = (float*)(ws + 13369344);        // 256x2304 f32
  unsigned short* Esb = (unsigned short*)(ws + 15728640); // 256x3072 bf16
  unsigned short* Etb = (unsigned short*)(ws + 17301504); // 256x3072 bf16

  hipLaunchKernelGGL(cvt_kernel, dim3(2048), dim3(256), 0, stream,
      (const float4*)hidden, (const float4*)W_src, (const float4*)W_tgt,
      (const float4*)dense_W, (us4*)Ab, (us4*)Wb);
  hipLaunchKernelGGL(gemm_kernel, dim3(132, 4), dim3(256), 0, stream,
      Ab, Wb, b_src, b_tgt, dense_b, out, z, Esb, Etb);
  hipLaunchKernelGGL(pair_kernel, dim3(8, 8, 9), dim3(512), 0, stream,
      Esb, Etb, w_out, z, clf_W, clf_b, out + OFF_REL);
}

// Round 20
// 43.705 us; speedup vs baseline: 1.0968x; 1.0968x over previous
//
#include <hip/hip_runtime.h>
#include <hip/hip_bf16.h>

#define LL 128
#define HH 768
#define OFF_REL  0
#define OFF_MASK 131072
#define OFF_HSRC 131840
#define OFF_HTGT 918272
#define SCALEC 2.8853900817779268f   // 2*log2(e):  e^{2x} = exp2(SCALEC*x)

typedef __attribute__((ext_vector_type(8))) short short8;
typedef __attribute__((ext_vector_type(4))) float floatx4;

__device__ inline unsigned short f2bf(float f) {
  unsigned u = __float_as_uint(f);
  u += 0x7FFFu + ((u >> 16) & 1u);
  return (unsigned short)(u >> 16);
}
struct us4 { unsigned short x, y, z, w; };

__device__ __forceinline__ void gload16(const void* g, void* l) {
  __builtin_amdgcn_global_load_lds(
      (const __attribute__((address_space(1))) unsigned int*)g,
      (__attribute__((address_space(3))) unsigned int*)l,
      16, 0, 0);
}

// ---------------- fp32 -> bf16: hidden + all three weights ----------------
__global__ __launch_bounds__(256) void cvt_kernel(
    const float4* __restrict__ hs, const float4* __restrict__ wsrc,
    const float4* __restrict__ wtgt, const float4* __restrict__ wd,
    us4* __restrict__ ab, us4* __restrict__ wb)
{
  const int n0 = 49152;
  const int n1 = n0 + 589824;
  const int n2 = n1 + 589824;
  const int n3 = n2 + 442368;
  int stride = gridDim.x * blockDim.x;
  for (int i = blockIdx.x * blockDim.x + threadIdx.x; i < n3; i += stride) {
    const float4* src; us4* dst;
    if (i < n0)      { src = hs   + i;        dst = ab + i; }
    else if (i < n1) { src = wsrc + (i - n0); dst = wb + (i - n0); }
    else if (i < n2) { src = wtgt + (i - n1); dst = wb + 589824 + (i - n1); }
    else             { src = wd   + (i - n2); dst = wb + 1179648 + (i - n2); }
    float4 v = *src;
    us4 o; o.x = f2bf(v.x); o.y = f2bf(v.y); o.z = f2bf(v.z); o.w = f2bf(v.w);
    *dst = o;
  }
}

// ---------------- GEMM: depth-3 counted-vmcnt pipeline, BK=64, XOR-swizzled LDS ----------------
// grid (132,4) x 256 thr. Tile 64x64, 12 K-steps. 4 LDS buffers (64 KB), 3 batches
// in flight (16 loads), s_waitcnt vmcnt(12) steady state. Swizzle: LDS (row,c16)
// holds global (row, c16 ^ (row&7)); reads use the same involution -> ~2-way banks.
__global__ __launch_bounds__(256, 2) void gemm_kernel(
    const unsigned short* __restrict__ Ab, const unsigned short* __restrict__ Wb,
    const float* __restrict__ b_src, const float* __restrict__ b_tgt,
    const float* __restrict__ dense_b,
    float* __restrict__ out, float* __restrict__ z,
    float* __restrict__ Es, float* __restrict__ Et)
{
  // buffer: A [64][64] bf16 @0 (8 KB), B [64][64] bf16 @8192. 4 buffers = 64 KB.
  __shared__ __align__(1024) char sAB[4][16384];
  int tid = threadIdx.x;
  int wave = tid >> 6, lane = tid & 63;
  int nb = blockIdx.x, rb = blockIdx.y;
  int gcol0 = nb * 64, grow0 = rb * 64;
  int which = (nb < 48) ? 0 : (nb < 96) ? 1 : 2;

  // staging: linear idx = tid + j*256 -> row = idx>>3, c16 = idx&7.
  // global col pre-swizzled: c16s = c16 ^ (row&7)  (row+32 keeps row&7).
  int r0 = tid >> 3, c0 = tid & 7;
  int c0s = c0 ^ (r0 & 7);
  const unsigned short* gA0 = Ab + (long)(grow0 + r0) * HH + c0s * 8;
  const unsigned short* gA1 = gA0 + 32 * HH;
  const unsigned short* gB0 = Wb + (long)(gcol0 + r0) * HH + c0s * 8;
  const unsigned short* gB1 = gB0 + 32 * HH;

  // fragment roles
  int lr = lane & 15, hi = lane >> 4;
  int wm = (wave >> 1) * 32, wn = (wave & 1) * 32;
  int swz = lr & 7;

  floatx4 acc[2][2];
  #pragma unroll
  for (int mi = 0; mi < 2; ++mi)
    #pragma unroll
    for (int ni = 0; ni < 2; ++ni)
      acc[mi][ni] = (floatx4){0.f, 0.f, 0.f, 0.f};

#define STAGE(BUF, KT) do {                                       \
    char* b_ = &sAB[BUF][0];                                      \
    gload16(gA0 + (KT) * 64, b_ + wave * 1024);                   \
    gload16(gA1 + (KT) * 64, b_ + 4096 + wave * 1024);            \
    gload16(gB0 + (KT) * 64, b_ + 8192 + wave * 1024);            \
    gload16(gB1 + (KT) * 64, b_ + 12288 + wave * 1024);           \
  } while (0)

  STAGE(0, 0);
  STAGE(1, 1);
  STAGE(2, 2);

  #pragma unroll
  for (int kt = 0; kt < 12; ++kt) {
    int buf = kt & 3;
    if (kt <= 8) {
      STAGE((kt + 3) & 3, kt + 3);
      asm volatile("s_waitcnt vmcnt(12)" ::: "memory");  // batch kt landed; 12 in flight
    } else if (kt == 9) {
      asm volatile("s_waitcnt vmcnt(8)" ::: "memory");
    } else if (kt == 10) {
      asm volatile("s_waitcnt vmcnt(4)" ::: "memory");
    } else {
      asm volatile("s_waitcnt vmcnt(0)" ::: "memory");
    }
    __builtin_amdgcn_sched_barrier(0);
    __builtin_amdgcn_s_barrier();                        // raw: loads stay in flight
    __builtin_amdgcn_sched_barrier(0);

    const char* bA = &sAB[buf][0];
    const char* bB = bA + 8192;
    #pragma unroll
    for (int ks = 0; ks < 2; ++ks) {
      int cs = ((ks * 4 + hi) ^ swz) * 16;
      short8 a0 = *(const short8*)(bA + (wm + lr) * 128 + cs);
      short8 a1 = *(const short8*)(bA + (wm + 16 + lr) * 128 + cs);
      short8 b0 = *(const short8*)(bB + (wn + lr) * 128 + cs);
      short8 b1 = *(const short8*)(bB + (wn + 16 + lr) * 128 + cs);
      acc[0][0] = __builtin_amdgcn_mfma_f32_16x16x32_bf16(a0, b0, acc[0][0], 0, 0, 0);
      acc[0][1] = __builtin_amdgcn_mfma_f32_16x16x32_bf16(a0, b1, acc[0][1], 0, 0, 0);
      acc[1][0] = __builtin_amdgcn_mfma_f32_16x16x32_bf16(a1, b0, acc[1][0], 0, 0, 0);
      acc[1][1] = __builtin_amdgcn_mfma_f32_16x16x32_bf16(a1, b1, acc[1][1], 0, 0, 0);
    }

    __builtin_amdgcn_sched_barrier(0);
    __builtin_amdgcn_s_barrier();                        // protect buf before re-stage
  }
#undef STAGE

  // epilogue (validated mapping)
  int lrow = hi * 4;
  #pragma unroll
  for (int mi = 0; mi < 2; ++mi)
  #pragma unroll
  for (int ni = 0; ni < 2; ++ni) {
    int colg = gcol0 + wn + ni * 16 + lr;
    int row0 = grow0 + wm + mi * 16 + lrow;
    if (which == 0) {
      float bv = b_src[colg];
      #pragma unroll
      for (int r2 = 0; r2 < 4; ++r2) {
        int row = row0 + r2;
        float v = acc[mi][ni][r2] + bv;
        out[OFF_HSRC + row * 3072 + colg] = v;
        Es[row * 3072 + colg] = __builtin_amdgcn_exp2f(SCALEC * v);
      }
    } else if (which == 1) {
      int cc = colg - 3072;
      float bv = b_tgt[cc];
      #pragma unroll
      for (int r2 = 0; r2 < 4; ++r2) {
        int row = row0 + r2;
        float v = acc[mi][ni][r2] + bv;
        out[OFF_HTGT + row * 3072 + cc] = v;
        Et[row * 3072 + cc] = __builtin_amdgcn_exp2f(SCALEC * v);
      }
    } else {
      int cc = colg - 6144;
      float bv = dense_b[cc];
      #pragma unroll
      for (int r2 = 0; r2 < 4; ++r2)
        z[(row0 + r2) * 2304 + cc] = acc[mi][ni][r2] + bv;
    }
  }
}

// ---------------- pairwise relation + token-mask head ----------------
#define PHC 256
__global__ __launch_bounds__(512) void pair_kernel(
    const float* __restrict__ Es, const float* __restrict__ Et,
    const float* __restrict__ w_out,
    const float* __restrict__ z, const float* __restrict__ clf_W,
    const float* __restrict__ clf_b, float* __restrict__ out)
{
  int tid = threadIdx.x;

  if (blockIdx.z == 8) {
    int blk = blockIdx.y * 8 + blockIdx.x;
    int wave = tid >> 6, lane = tid & 63;
    int slot = blk * 8 + wave;
    for (int o = slot; o < 768; o += 512) {
      int b = o / 384, rem = o - b * 384;
      int t = rem >> 7, lt = rem & 127;
      const float* zr = z + (long)(b * LL + lt) * 2304 + t * HH;
      float acc = 0.f;
      for (int h = lane; h < HH; h += 64) {
        float x = zr[h];
        float th = 1.f - 2.f * __builtin_amdgcn_rcpf(1.f + __builtin_amdgcn_exp2f(SCALEC * x));
        acc = fmaf(clf_W[h], th, acc);
      }
      #pragma unroll
      for (int d = 32; d; d >>= 1) acc += __shfl_down(acc, d);
      if (lane == 0) out[OFF_MASK + o] = acc + clf_b[0];
    }
    return;
  }

  __shared__ float sA[16][PHC + 4];
  __shared__ float sB[16][PHC + 4];
  __shared__ float sRed[2048];
  __shared__ float sWsum;

  int g = tid >> 6, lane = tid & 63;
  int sq = lane >> 3, tq = lane & 7;
  int t0 = blockIdx.x * 16, s0 = blockIdx.y * 16;
  int br = blockIdx.z, bb = br >> 2, r = br & 3;

  if (tid < 64) {
    float wsm = 0.f;
    for (int h = tid; h < HH; h += 64) wsm += w_out[h];
    #pragma unroll
    for (int d = 32; d; d >>= 1) wsm += __shfl_down(wsm, d);
    if (tid == 0) sWsum = wsm;
  }

  float a00 = 0.f, a01 = 0.f, a10 = 0.f, a11 = 0.f;

  for (int c = 0; c < HH; c += PHC) {
    int offu = __builtin_amdgcn_readfirstlane(c + g * 32);
    float4 wv[8];
    #pragma unroll
    for (int q = 0; q < 8; ++q) wv[q] = *(const float4*)(w_out + offu + q * 4);

    __syncthreads();
    #pragma unroll
    for (int j = 0; j < 2; ++j) {
      int idx = tid * 2 + j;
      int row = idx >> 6, col4 = (idx & 63) * 4;
      *(float4*)&sA[row][col4] =
          *(const float4*)(Es + (long)(bb * LL + s0 + row) * 3072 + r * HH + c + col4);
      *(float4*)&sB[row][col4] =
          *(const float4*)(Et + (long)(bb * LL + t0 + row) * 3072 + r * HH + c + col4);
    }
    __syncthreads();

    const float* pA0 = &sA[2 * sq][g * 32];
    const float* pA1 = &sA[2 * sq + 1][g * 32];
    const float* pB0 = &sB[2 * tq][g * 32];
    const float* pB1 = &sB[2 * tq + 1][g * 32];
    #pragma unroll
    for (int hh = 0; hh < 32; hh += 4) {
      float4 e0 = *(const float4*)(pA0 + hh);
      float4 e1 = *(const float4*)(pA1 + hh);
      float4 f0 = *(const float4*)(pB0 + hh);
      float4 f1 = *(const float4*)(pB1 + hh);
      float4 vw = wv[hh >> 2];
      a00 = fmaf(vw.x, __builtin_amdgcn_rcpf(fmaf(e0.x, f0.x, 1.f)), a00);
      a01 = fmaf(vw.x, __builtin_amdgcn_rcpf(fmaf(e0.x, f1.x, 1.f)), a01);
      a10 = fmaf(vw.x, __builtin_amdgcn_rcpf(fmaf(e1.x, f0.x, 1.f)), a10);
      a11 = fmaf(vw.x, __builtin_amdgcn_rcpf(fmaf(e1.x, f1.x, 1.f)), a11);
      a00 = fmaf(vw.y, __builtin_amdgcn_rcpf(fmaf(e0.y, f0.y, 1.f)), a00);
      a01 = fmaf(vw.y, __builtin_amdgcn_rcpf(fmaf(e0.y, f1.y, 1.f)), a01);
      a10 = fmaf(vw.y, __builtin_amdgcn_rcpf(fmaf(e1.y, f0.y, 1.f)), a10);
      a11 = fmaf(vw.y, __builtin_amdgcn_rcpf(fmaf(e1.y, f1.y, 1.f)), a11);
      a00 = fmaf(vw.z, __builtin_amdgcn_rcpf(fmaf(e0.z, f0.z, 1.f)), a00);
      a01 = fmaf(vw.z, __builtin_amdgcn_rcpf(fmaf(e0.z, f1.z, 1.f)), a01);
      a10 = fmaf(vw.z, __builtin_amdgcn_rcpf(fmaf(e1.z, f0.z, 1.f)), a10);
      a11 = fmaf(vw.z, __builtin_amdgcn_rcpf(fmaf(e1.z, f1.z, 1.f)), a11);
      a00 = fmaf(vw.w, __builtin_amdgcn_rcpf(fmaf(e0.w, f0.w, 1.f)), a00);
      a01 = fmaf(vw.w, __builtin_amdgcn_rcpf(fmaf(e0.w, f1.w, 1.f)), a01);
      a10 = fmaf(vw.w, __builtin_amdgcn_rcpf(fmaf(e1.w, f0.w, 1.f)), a10);
      a11 = fmaf(vw.w, __builtin_amdgcn_rcpf(fmaf(e1.w, f1.w, 1.f)), a11);
    }
  }

  sRed[0 * 512 + g * 64 + lane] = a00;
  sRed[1 * 512 + g * 64 + lane] = a01;
  sRed[2 * 512 + g * 64 + lane] = a10;
  sRed[3 * 512 + g * 64 + lane] = a11;
  __syncthreads();
  if (tid < 256) {
    int s = tid >> 4, t = tid & 15;
    int pp = (s >> 1) * 8 + (t >> 1);
    int sl = (s & 1) * 2 + (t & 1);
    float sum = 0.f;
    #pragma unroll
    for (int gg = 0; gg < 8; ++gg) sum += sRed[sl * 512 + gg * 64 + pp];
    out[((long)br * LL + (s0 + s)) * LL + (t0 + t)] = sWsum - 2.f * sum;
  }
}

extern "C" void kernel_launch(void* const* d_in, const int* in_sizes, int n_in,
                              void* d_out, int out_size, void* d_ws, size_t ws_size,
                              hipStream_t stream)
{
  const float* hidden  = (const float*)d_in[0];
  const float* W_src   = (const float*)d_in[1];
  const float* b_src   = (const float*)d_in[2];
  const float* W_tgt   = (const float*)d_in[3];
  const float* b_tgt   = (const float*)d_in[4];
  const float* w_out   = (const float*)d_in[5];
  const float* dense_W = (const float*)d_in[6];
  const float* dense_b = (const float*)d_in[7];
  const float* clf_W   = (const float*)d_in[8];
  const float* clf_b   = (const float*)d_in[9];
  float* out = (float*)d_out;
  char* ws = (char*)d_ws;

  unsigned short* Ab = (unsigned short*)ws;            // 256x768 bf16
  unsigned short* Wb = (unsigned short*)(ws + 393216); // 8448x768 bf16
  float* z  = (float*)(ws + 13369344);                 // 256x2304 f32
  float* Es = (float*)(ws + 15728640);                 // 256x3072 f32
  float* Et = (float*)(ws + 18874368);                 // 256x3072 f32

  hipLaunchKernelGGL(cvt_kernel, dim3(2048), dim3(256), 0, stream,
      (const float4*)hidden, (const float4*)W_src, (const float4*)W_tgt,
      (const float4*)dense_W, (us4*)Ab, (us4*)Wb);
  hipLaunchKernelGGL(gemm_kernel, dim3(132, 4), dim3(256), 0, stream,
      Ab, Wb, b_src, b_tgt, dense_b, out, z, Es, Et);
  hipLaunchKernelGGL(pair_kernel, dim3(8, 8, 9), dim3(512), 0, stream,
      Es, Et, w_out, z, clf_W, clf_b, out + OFF_REL);
}